// Round 7
// baseline (269.262 us; speedup 1.0000x reference)
//
#include <hip/hip_runtime.h>
#include <math.h>

#define B_   8
#define C_   512
#define CQ   64
#define N_   4096
#define EPSF 1e-6f
#define LS   40    // LDS row stride (shorts) for 32-wide k chunks (k3)
#define LS2  72    // LDS row stride (shorts) for 64-wide k (k4)
#define LSX  520   // k12 [n][ch] slab stride (swizzled slots)
#define LSC  68    // k12 [ch][n] slab stride: 64 + 4 pad (16B-aligned rows)
#define LSK2 72    // k12 Kn tile stride: 64 + 8 pad (16B-aligned rows)

typedef short  shortx8 __attribute__((ext_vector_type(8)));
typedef short  shortx4 __attribute__((ext_vector_type(4)));
typedef short  shortx2 __attribute__((ext_vector_type(2)));
typedef float  floatx4 __attribute__((ext_vector_type(4)));

__device__ __forceinline__ short f2bf(float f) {
    unsigned u = __builtin_bit_cast(unsigned, f);
    u += 0x7FFFu + ((u >> 16) & 1u);
    return (short)(u >> 16);
}
__device__ __forceinline__ float bf2f(short h) {
    unsigned u = ((unsigned)(unsigned short)h) << 16;
    return __builtin_bit_cast(float, u);
}
__device__ __forceinline__ shortx8 ldf8(const short* p) {
    return *(const shortx8*)p;
}

// ---------------------------------------------------------------------------
// P: cast weights to bf16. Wqk[128][512] = [Wq;Wk], Wvb[512][512].
// ---------------------------------------------------------------------------
__global__ __launch_bounds__(256) void pcast(
    const float* __restrict__ Wq, const float* __restrict__ Wk,
    const float* __restrict__ Wv, short* __restrict__ Wqk, short* __restrict__ Wvb)
{
    int i = (blockIdx.x * 256 + threadIdx.x) * 4;
    float4 v; short* dst;
    if (i < 2 * CQ * C_) {
        const float* src = (i < CQ * C_) ? (Wq + i) : (Wk + i - CQ * C_);
        v = *(const float4*)src;
        dst = Wqk + i;
    } else {
        int j = i - 2 * CQ * C_;
        v = *(const float4*)(Wv + j);
        dst = Wvb + j;
    }
    const float* f = (const float*)&v;
    shortx4 o = { f2bf(f[0]), f2bf(f[1]), f2bf(f[2]), f2bf(f[3]) };
    *(shortx4*)dst = o;
}

// ---------------------------------------------------------------------------
// K12 (fused k1+k2): per (n-tile 64, b):
//  stage x-slab once in BOTH orientations (xn_l [n][ch] swizzled for QK;
//  xc_l [ch][n] for the rank-update) + xsum partials (fp32, exact);
//  QK = [Wq;Wk] @ x (A = Wqk direct global->reg, L2-hot), +bias, L2-norm;
//  waveM==0 -> Qnt global; waveM==1 -> Kn tile to LDS (bf16) + Ksum atomics;
//  then KX[64m][512j] += Kn_tile @ slab^T entirely from LDS (atomic fp32).
// x is read ONCE for the whole pipeline; Kn never touches global; k2 deleted.
// grid (nt=64, b=8) = 512 blocks, 512 threads (8 waves); LDS ~142.5 KB ->
// 1 block/CU, 2 waves/SIMD. Only 2 barriers total.
// ---------------------------------------------------------------------------
__global__ __launch_bounds__(512, 1) void k12(
    const float* __restrict__ x, const short* __restrict__ Wqk,
    const float* __restrict__ bq, const float* __restrict__ bk,
    short* __restrict__ Qnt, float* __restrict__ Ksum,
    float* __restrict__ xsum, float* __restrict__ KX)
{
    const int b   = blockIdx.y;
    const int n0  = blockIdx.x * 64;
    const int tid = threadIdx.x;            // 0..511
    const int lane = tid & 63, wid = tid >> 6;   // 8 waves
    const int waveM = wid >> 2, waveN = wid & 3;
    const int quad = lane >> 4, ln = lane & 15;

    __shared__ __attribute__((aligned(16))) short xn_l[64][LSX];  // 66.6 KB
    __shared__ __attribute__((aligned(16))) short xc_l[512][LSC]; // 69.6 KB
    __shared__ __attribute__((aligned(16))) short Kn_l[64][LSK2]; //  9.2 KB
    __shared__ float bias_l[128];

    if (tid < 128) bias_l[tid] = (tid < 64) ? bq[tid] : bk[tid - 64];

    // ---- stage: thread (nq = n-quad, kp = ch-pair 0..31); 8 iters over ch ----
    const int nq = tid & 15, kp = tid >> 4;
    const float* xb = x + (size_t)b * C_ * N_;
#pragma unroll
    for (int i = 0; i < 8; i++) {
        const int ch = kp * 2 + 64 * i;
        const float* p = xb + (size_t)ch * N_ + n0 + nq * 4;
        float4 r0 = *(const float4*)(p);
        float4 r1 = *(const float4*)(p + N_);
        const float* f0 = (const float*)&r0;
        const float* f1 = (const float*)&r1;
        const int slot = ch >> 3, sub = ch & 7;   // sub even, sub+1 <= 7
        shortx4 o0, o1;
        float s0 = 0.f, s1 = 0.f;
#pragma unroll
        for (int j = 0; j < 4; j++) {
            o0[j] = f2bf(f0[j]); s0 += f0[j];
            o1[j] = f2bf(f1[j]); s1 += f1[j];
            const int n = nq * 4 + j;
            const int pcol = ((slot ^ ((n >> 2) & 7)) << 3) + sub;
            shortx2 t = { o0[j], o1[j] };
            *(shortx2*)&xn_l[n][pcol] = t;
        }
        *(shortx4*)&xc_l[ch][nq * 4]     = o0;
        *(shortx4*)&xc_l[ch + 1][nq * 4] = o1;
        // xsum partial (fp32 exact): reduce over the 16 nq-lanes of this quadrant
        s0 += __shfl_xor(s0, 1); s0 += __shfl_xor(s0, 2);
        s0 += __shfl_xor(s0, 4); s0 += __shfl_xor(s0, 8);
        s1 += __shfl_xor(s1, 1); s1 += __shfl_xor(s1, 2);
        s1 += __shfl_xor(s1, 4); s1 += __shfl_xor(s1, 8);
        if (nq == 0) {
            atomicAdd(&xsum[b * C_ + ch],     s0);
            atomicAdd(&xsum[b * C_ + ch + 1], s1);
        }
    }
    __syncthreads();

    // ---- QK: barrier-free; A = Wqk global->reg (L2-hot), B from xn_l ----
    const short* Ab = Wqk + (size_t)(waveM * 64 + ln) * C_ + quad * 8;
    const floatx4 z4 = {0.f, 0.f, 0.f, 0.f};
    floatx4 acc[4] = {z4, z4, z4, z4};

#pragma unroll 4
    for (int kc = 0; kc < 16; ++kc) {
        shortx8 af[4];
#pragma unroll
        for (int mt = 0; mt < 4; mt++)
            af[mt] = ldf8(Ab + (size_t)mt * 16 * C_ + kc * 32);
        const int row = waveN * 16 + ln;
        const int pslot = (kc * 4 + quad) ^ ((row >> 2) & 7);
        shortx8 bf8 = ldf8(&xn_l[row][pslot << 3]);
#pragma unroll
        for (int mt = 0; mt < 4; mt++)
            acc[mt] = __builtin_amdgcn_mfma_f32_16x16x32_bf16(af[mt], bf8, acc[mt], 0, 0, 0);
    }

    // bias
#pragma unroll
    for (int mt = 0; mt < 4; mt++)
#pragma unroll
        for (int r = 0; r < 4; r++)
            acc[mt][r] += bias_l[waveM * 64 + mt * 16 + quad * 4 + r];

    // column L2 normalize (wave's 64 rows are exactly Q or exactly K)
    {
        float s = 0.f;
#pragma unroll
        for (int mt = 0; mt < 4; mt++)
#pragma unroll
            for (int r = 0; r < 4; r++) s += acc[mt][r] * acc[mt][r];
        s += __shfl_xor(s, 16);
        s += __shfl_xor(s, 32);
        float inv = rsqrtf(s);
#pragma unroll
        for (int mt = 0; mt < 4; mt++)
#pragma unroll
            for (int r = 0; r < 4; r++) acc[mt][r] *= inv;
    }

    const int n = n0 + waveN * 16 + ln;
    if (waveM == 0) {            // Qn^T [n][m] -> global (needed by k4)
        short* Qb = Qnt + (size_t)b * N_ * CQ;
#pragma unroll
        for (int mt = 0; mt < 4; mt++) {
            shortx4 v;
#pragma unroll
            for (int r = 0; r < 4; r++) v[r] = f2bf(acc[mt][r]);
            *(shortx4*)(Qb + (size_t)n * CQ + mt * 16 + quad * 4) = v;
        }
    } else {                     // Kn tile -> LDS (bf16) + Ksum atomics
#pragma unroll
        for (int mt = 0; mt < 4; mt++)
#pragma unroll
            for (int r = 0; r < 4; r++) {
                int m = mt * 16 + quad * 4 + r;
                float v = acc[mt][r];
                Kn_l[m][waveN * 16 + ln] = f2bf(v);
                float s = v;
                s += __shfl_xor(s, 1); s += __shfl_xor(s, 2);
                s += __shfl_xor(s, 4); s += __shfl_xor(s, 8);
                if (ln == 0) atomicAdd(&Ksum[b * CQ + m], s);
            }
    }
    __syncthreads();

    // ---- KX rank-update: KX[m][j] += Kn_tile[m][:] . xc_l[j][:] (k = n) ----
    floatx4 acc2[4][4];
#pragma unroll
    for (int i = 0; i < 4; i++)
#pragma unroll
        for (int j = 0; j < 4; j++) acc2[i][j] = z4;

    const int j0w = wid * 64;    // each wave owns 64 j-channels
#pragma unroll
    for (int kc2 = 0; kc2 < 2; kc2++) {
        shortx8 aK[4];
#pragma unroll
        for (int mt = 0; mt < 4; mt++)
            aK[mt] = ldf8(&Kn_l[mt * 16 + ln][kc2 * 32 + quad * 8]);
#pragma unroll
        for (int jt = 0; jt < 4; jt++) {
            shortx8 bX = ldf8(&xc_l[j0w + jt * 16 + ln][kc2 * 32 + quad * 8]);
#pragma unroll
            for (int mt = 0; mt < 4; mt++)
                acc2[mt][jt] = __builtin_amdgcn_mfma_f32_16x16x32_bf16(aK[mt], bX, acc2[mt][jt], 0, 0, 0);
        }
    }

    float* KXb = KX + (size_t)b * CQ * C_;
#pragma unroll
    for (int mt = 0; mt < 4; mt++)
#pragma unroll
        for (int jt = 0; jt < 4; jt++)
#pragma unroll
            for (int r = 0; r < 4; r++) {
                int m = mt * 16 + quad * 4 + r;
                atomicAdd(&KXb[(size_t)m * C_ + j0w + jt * 16 + ln], acc2[mt][jt][r]);
            }
}

// ---------------------------------------------------------------------------
// K3: Mt[c][m] = sum_j Wv[c][j]*KX[m][j] + Ksum[m]*bv[c]  (bf16 out, full j)
//     vs[c] = sum_j Wv[c][j]*xsum[j] + N*bv[c]
// grid (ct=8, b=8) = 64 blocks.  (round-0 verbatim)
// ---------------------------------------------------------------------------
__global__ __launch_bounds__(256, 2) void k3_m(
    const float* __restrict__ KX, const short* __restrict__ Wvb,
    const float* __restrict__ bv, const float* __restrict__ Ksum,
    const float* __restrict__ xsum,
    short* __restrict__ Mt, float* __restrict__ vs)
{
    const int ct = blockIdx.x, b = blockIdx.y;
    const int c0 = ct * 64;
    const int tid = threadIdx.x;
    const int lane = tid & 63, wid = tid >> 6;
    const int quad = lane >> 4, ln = lane & 15;

    __shared__ short A_l[2][64][LS];   // Wv rows c
    __shared__ short B_l[2][64][LS];   // KX rows m (bf16)
    __shared__ float xsl[C_], Ksl[64], bvl[64], vsp[4][64];

    xsl[tid] = xsum[(size_t)b * C_ + tid];
    xsl[tid + 256] = xsum[(size_t)b * C_ + tid + 256];
    if (tid < 64) { Ksl[tid] = Ksum[b * CQ + tid]; bvl[tid] = bv[c0 + tid]; }

    const int rA = tid >> 2, oA = (tid & 3) * 8;
    const short* As = Wvb + (size_t)(c0 + rA) * C_ + oA;
    const float* Bs = KX + ((size_t)b * CQ + rA) * C_ + oA;

    shortx8 aC = *(const shortx8*)As;
    float4 b0 = *(const float4*)(Bs);
    float4 b1 = *(const float4*)(Bs + 4);

    auto stage = [&](int buf, shortx8 a, float4 q0, float4 q1) {
        *(shortx8*)&A_l[buf][rA][oA] = a;
        const float* f0 = (const float*)&q0;
        const float* f1 = (const float*)&q1;
        shortx8 t;
#pragma unroll
        for (int i = 0; i < 4; i++) { t[i] = f2bf(f0[i]); t[i + 4] = f2bf(f1[i]); }
        *(shortx8*)&B_l[buf][rA][oA] = t;
    };
    stage(0, aC, b0, b1);
    __syncthreads();

    const floatx4 z4 = {0.f, 0.f, 0.f, 0.f};
    floatx4 acc[4] = {z4, z4, z4, z4};
    float vsacc = 0.f;
    const int cv = tid & 63;

    int cur = 0;
    for (int it = 0; it < 16; ++it) {
        shortx8 aN; float4 n0v, n1v;
        if (it < 15) {
            const int off = (it + 1) * 32;
            aN  = *(const shortx8*)(As + off);
            n0v = *(const float4*)(Bs + off);
            n1v = *(const float4*)(Bs + off + 4);
        }
        shortx8 af[4];
#pragma unroll
        for (int ct2 = 0; ct2 < 4; ct2++)
            af[ct2] = ldf8(&A_l[cur][ct2 * 16 + ln][quad * 8]);
        shortx8 bf8 = ldf8(&B_l[cur][wid * 16 + ln][quad * 8]);
#pragma unroll
        for (int ct2 = 0; ct2 < 4; ct2++)
            acc[ct2] = __builtin_amdgcn_mfma_f32_16x16x32_bf16(af[ct2], bf8, acc[ct2], 0, 0, 0);
        // vs partial from staged Wv tile
#pragma unroll
        for (int jj = 0; jj < 8; jj++)
            vsacc += bf2f(A_l[cur][cv][wid * 8 + jj]) * xsl[it * 32 + wid * 8 + jj];
        if (it < 15) stage(cur ^ 1, aN, n0v, n1v);
        __syncthreads();
        cur ^= 1;
    }

    vsp[wid][cv] = vsacc;
    __syncthreads();
    if (tid < 64)
        vs[(size_t)b * C_ + c0 + tid] =
            vsp[0][tid] + vsp[1][tid] + vsp[2][tid] + vsp[3][tid] + (float)N_ * bvl[tid];

    const int m = wid * 16 + ln;
    const float ksm = Ksl[m];
    short* Mb = Mt + (size_t)b * C_ * CQ;
#pragma unroll
    for (int ct2 = 0; ct2 < 4; ct2++)
#pragma unroll
        for (int r = 0; r < 4; r++) {
            int c = ct2 * 16 + quad * 4 + r;
            Mb[(size_t)(c0 + c) * CQ + m] = f2bf(acc[ct2][r] + ksm * bvl[c]);
        }
}

// ---------------------------------------------------------------------------
// K4: ts[n] = 1/(N + Qn[:,n].(Ksum+eps));
//     out[c][n] = gamma*ts[n]*(vs[c] + sum_m Qn[m][n]*Mt[c][m])
// grid (nt=32, ct=4, b=8), block 256.  (round-0 verbatim)
// ---------------------------------------------------------------------------
__global__ __launch_bounds__(256, 3) void k4_out(
    const short* __restrict__ Qnt, const short* __restrict__ Mt,
    const float* __restrict__ vs, const float* __restrict__ Ksum,
    const float* __restrict__ gamma, float* __restrict__ out)
{
    const int nt = blockIdx.x, ct = blockIdx.y, b = blockIdx.z;
    const int n0 = nt * 128, c0 = ct * 128;
    const int tid = threadIdx.x;
    const int lane = tid & 63, wid = tid >> 6;
    const int waveC = wid >> 1, waveN = wid & 1;
    const int quad = lane >> 4, ln = lane & 15;

    __shared__ short A_l[128][LS2];   // Mt rows c (bf16), k=m
    __shared__ short B_l[128][LS2];   // Qnt rows n (bf16)
    __shared__ float tsl[128], vsl[128], Ks_l[64];

    {
        int c = tid >> 1, h = tid & 1;
        const short* src = Mt + ((size_t)b * C_ + c0 + c) * CQ + h * 32;
#pragma unroll
        for (int q = 0; q < 4; q++)
            *(shortx8*)&A_l[c][h * 32 + q * 8] = *(const shortx8*)(src + q * 8);
    }
    {
        int n = tid >> 1, h = tid & 1;
        const short* src = Qnt + ((size_t)b * N_ + n0 + n) * CQ + h * 32;
#pragma unroll
        for (int q = 0; q < 4; q++)
            *(shortx8*)&B_l[n][h * 32 + q * 8] = *(const shortx8*)(src + q * 8);
    }
    if (tid < 64)  Ks_l[tid] = Ksum[b * CQ + tid];
    if (tid < 128) vsl[tid]  = vs[(size_t)b * C_ + c0 + tid];
    __syncthreads();

    if (tid < 128) {
        const short* row = B_l[tid];
        float s = 0.f;
#pragma unroll
        for (int m = 0; m < 64; m++) s += bf2f(row[m]) * (Ks_l[m] + EPSF);
        tsl[tid] = 1.f / ((float)N_ + s);
    }
    __syncthreads();

    const floatx4 z4 = {0.f, 0.f, 0.f, 0.f};
    floatx4 acc[4][4];
#pragma unroll
    for (int i = 0; i < 4; i++)
#pragma unroll
        for (int j = 0; j < 4; j++) acc[i][j] = z4;

#pragma unroll
    for (int kc = 0; kc < 2; kc++) {
        shortx8 af[4];
#pragma unroll
        for (int ct2 = 0; ct2 < 4; ct2++)
            af[ct2] = ldf8(&A_l[waveC * 64 + ct2 * 16 + ln][kc * 32 + quad * 8]);
#pragma unroll
        for (int nt2 = 0; nt2 < 4; nt2++) {
            shortx8 bf8 = ldf8(&B_l[waveN * 64 + nt2 * 16 + ln][kc * 32 + quad * 8]);
#pragma unroll
            for (int ct2 = 0; ct2 < 4; ct2++)
                acc[ct2][nt2] = __builtin_amdgcn_mfma_f32_16x16x32_bf16(af[ct2], bf8, acc[ct2][nt2], 0, 0, 0);
        }
    }

    const float g = gamma[0];
    float* ob = out + (size_t)b * C_ * N_;
#pragma unroll
    for (int ct2 = 0; ct2 < 4; ct2++)
#pragma unroll
        for (int r = 0; r < 4; r++) {
            int cl = waveC * 64 + ct2 * 16 + quad * 4 + r;
            float vc = vsl[cl];
#pragma unroll
            for (int nt2 = 0; nt2 < 4; nt2++) {
                int nl = waveN * 64 + nt2 * 16 + ln;
                ob[(size_t)(c0 + cl) * N_ + n0 + nl] = g * tsl[nl] * (vc + acc[ct2][nt2][r]);
            }
        }
}

// ---------------------------------------------------------------------------
extern "C" void kernel_launch(void* const* d_in, const int* in_sizes, int n_in,
                              void* d_out, int out_size, void* d_ws, size_t ws_size,
                              hipStream_t stream)
{
    (void)in_sizes; (void)n_in; (void)out_size; (void)ws_size;
    const float* x     = (const float*)d_in[0];
    const float* Wq    = (const float*)d_in[1];
    const float* bq    = (const float*)d_in[2];
    const float* Wk    = (const float*)d_in[3];
    const float* bk    = (const float*)d_in[4];
    const float* Wv    = (const float*)d_in[5];
    const float* bv    = (const float*)d_in[6];
    const float* gamma = (const float*)d_in[7];
    float* out = (float*)d_out;

    short* Qnt = (short*)d_ws;                          // [8][4096][64] bf16
    float* Ksum = (float*)(Qnt + (size_t)B_ * N_ * CQ); // [8][64]
    float* xsum = Ksum + B_ * CQ;                       // [8][512]
    float* KX   = xsum + B_ * C_;                       // [8][64][512]
    short* Mt   = (short*)(KX + (size_t)B_ * CQ * C_);  // [8][512][64] bf16
    float* vs   = (float*)(Mt + (size_t)B_ * C_ * CQ);  // [8][512]
    short* Wqk  = (short*)(vs + B_ * C_);               // [128][512] bf16
    short* Wvb  = Wqk + 2 * CQ * C_;                    // [512][512] bf16

    size_t zbytes = (size_t)(B_ * CQ + B_ * C_ + B_ * CQ * C_) * 4; // Ksum+xsum+KX
    hipMemsetAsync(Ksum, 0, zbytes, stream);

    pcast <<<dim3(320),      256, 0, stream>>>(Wq, Wk, Wv, Wqk, Wvb);
    k12   <<<dim3(64, 8),    512, 0, stream>>>(x, Wqk, bq, bk, Qnt, Ksum, xsum, KX);
    k3_m  <<<dim3(8, 8),     256, 0, stream>>>(KX, Wvb, bv, Ksum, xsum, Mt, vs);
    k4_out<<<dim3(32, 4, 8), 256, 0, stream>>>(Qnt, Mt, vs, Ksum, gamma, out);
}

// Round 8
// 188.801 us; speedup vs baseline: 1.4262x; 1.4262x over previous
//
#include <hip/hip_runtime.h>
#include <math.h>

#define B_   8
#define C_   512
#define CQ   64
#define N_   4096
#define EPSF 1e-6f
#define LS   40    // LDS row stride (shorts) for 32-wide k chunks; 80 B = 5x16 B
#define LS2  72    // LDS row stride (shorts) for 64-wide k (K4); 144 B = 9x16 B

typedef short  shortx8 __attribute__((ext_vector_type(8)));
typedef short  shortx4 __attribute__((ext_vector_type(4)));
typedef short  shortx2 __attribute__((ext_vector_type(2)));
typedef float  floatx4 __attribute__((ext_vector_type(4)));

__device__ __forceinline__ short f2bf(float f) {
    unsigned u = __builtin_bit_cast(unsigned, f);
    u += 0x7FFFu + ((u >> 16) & 1u);
    return (short)(u >> 16);
}
__device__ __forceinline__ float bf2f(short h) {
    unsigned u = ((unsigned)(unsigned short)h) << 16;
    return __builtin_bit_cast(float, u);
}
__device__ __forceinline__ shortx8 ldf8(const short* p) {
    return *(const shortx8*)p;
}

// ---------------------------------------------------------------------------
// P: cast weights to bf16. Wqk[128][512] = [Wq;Wk], Wvb[512][512].
// ---------------------------------------------------------------------------
__global__ __launch_bounds__(256) void pcast(
    const float* __restrict__ Wq, const float* __restrict__ Wk,
    const float* __restrict__ Wv, short* __restrict__ Wqk, short* __restrict__ Wvb)
{
    int i = (blockIdx.x * 256 + threadIdx.x) * 4;
    float4 v; short* dst;
    if (i < 2 * CQ * C_) {
        const float* src = (i < CQ * C_) ? (Wq + i) : (Wk + i - CQ * C_);
        v = *(const float4*)src;
        dst = Wqk + i;
    } else {
        int j = i - 2 * CQ * C_;
        v = *(const float4*)(Wv + j);
        dst = Wvb + j;
    }
    const float* f = (const float*)&v;
    shortx4 o = { f2bf(f[0]), f2bf(f[1]), f2bf(f[2]), f2bf(f[3]) };
    *(shortx4*)dst = o;
}

// ---------------------------------------------------------------------------
// K1: QK = [Wq;Wk] @ x (bf16 MFMA), +bias, column L2-norm;
//     emits Qnt[b][n][m] bf16, Kn[b][m][n] bf16, Ksum (atomic).
// ROUND-0 VERBATIM (best measured). grid (nt=64, b=8), block 256.
// ---------------------------------------------------------------------------
__global__ __launch_bounds__(256, 2) void k1_qk(
    const float* __restrict__ x, const short* __restrict__ Wqk,
    const float* __restrict__ bq, const float* __restrict__ bk,
    short* __restrict__ Qnt, short* __restrict__ Kn, float* __restrict__ Ksum)
{
    const int b   = blockIdx.y;
    const int n0  = blockIdx.x * 64;
    const int tid = threadIdx.x;
    const int lane = tid & 63, wid = tid >> 6;
    const int waveM = wid >> 1, waveN = wid & 1;
    const int quad = lane >> 4, ln = lane & 15;

    __shared__ short A_l[2][128][LS];   // [buf][m][k] Wqk bf16
    __shared__ short B_l[2][64][LS];    // [buf][n][k] x^T bf16
    __shared__ float bias_l[128];

    if (tid < 128) bias_l[tid] = (tid < 64) ? bq[tid] : bk[tid - 64];

    const int mA = tid >> 1, koA = (tid & 1) * 16;   // A: 128 m x 32 k
    const short* Asrc = Wqk + (size_t)mA * C_;
    const int kp = tid >> 4, nq = tid & 15;          // B: 2k x 4n per thread
    const float* xb = x + (size_t)b * C_ * N_;

    shortx8 a0 = *(const shortx8*)(Asrc + koA);
    shortx8 a1 = *(const shortx8*)(Asrc + koA + 8);
    float4 r0, r1;
    {
        const float* Bs = xb + (size_t)(kp * 2) * N_ + n0 + nq * 4;
        r0 = *(const float4*)(Bs);
        r1 = *(const float4*)(Bs + N_);
    }

    auto stage = [&](int buf, shortx8 s0, shortx8 s1, float4 q0, float4 q1) {
        *(shortx8*)&A_l[buf][mA][koA]     = s0;
        *(shortx8*)&A_l[buf][mA][koA + 8] = s1;
        const float* f0 = (const float*)&q0;
        const float* f1 = (const float*)&q1;
#pragma unroll
        for (int i = 0; i < 4; i++) {
            shortx2 t = { f2bf(f0[i]), f2bf(f1[i]) };
            *(shortx2*)&B_l[buf][nq * 4 + i][kp * 2] = t;
        }
    };
    stage(0, a0, a1, r0, r1);
    __syncthreads();

    const floatx4 z4 = {0.f, 0.f, 0.f, 0.f};
    floatx4 acc[4][2];
#pragma unroll
    for (int mt = 0; mt < 4; mt++) { acc[mt][0] = z4; acc[mt][1] = z4; }

    int cur = 0;
    for (int it = 0; it < 16; ++it) {
        shortx8 na0, na1; float4 nr0, nr1;
        if (it < 15) {
            const int k0 = (it + 1) * 32;
            na0 = *(const shortx8*)(Asrc + k0 + koA);
            na1 = *(const shortx8*)(Asrc + k0 + koA + 8);
            const float* Bs = xb + (size_t)(k0 + kp * 2) * N_ + n0 + nq * 4;
            nr0 = *(const float4*)(Bs);
            nr1 = *(const float4*)(Bs + N_);
        }
        shortx8 af[4];
#pragma unroll
        for (int mt = 0; mt < 4; mt++)
            af[mt] = ldf8(&A_l[cur][waveM * 64 + mt * 16 + ln][quad * 8]);
#pragma unroll
        for (int nt = 0; nt < 2; nt++) {
            shortx8 bf8 = ldf8(&B_l[cur][waveN * 32 + nt * 16 + ln][quad * 8]);
#pragma unroll
            for (int mt = 0; mt < 4; mt++)
                acc[mt][nt] = __builtin_amdgcn_mfma_f32_16x16x32_bf16(af[mt], bf8, acc[mt][nt], 0, 0, 0);
        }
        if (it < 15) stage(cur ^ 1, na0, na1, nr0, nr1);
        __syncthreads();
        cur ^= 1;
    }

    // bias
#pragma unroll
    for (int mt = 0; mt < 4; mt++)
#pragma unroll
        for (int r = 0; r < 4; r++) {
            float bias = bias_l[waveM * 64 + mt * 16 + quad * 4 + r];
#pragma unroll
            for (int nt = 0; nt < 2; nt++) acc[mt][nt][r] += bias;
        }
    // column L2 normalize (wave's 64 rows are exactly Q or exactly K)
#pragma unroll
    for (int nt = 0; nt < 2; nt++) {
        float s = 0.f;
#pragma unroll
        for (int mt = 0; mt < 4; mt++)
#pragma unroll
            for (int r = 0; r < 4; r++) s += acc[mt][nt][r] * acc[mt][nt][r];
        s += __shfl_xor(s, 16);
        s += __shfl_xor(s, 32);
        float inv = rsqrtf(s);
#pragma unroll
        for (int mt = 0; mt < 4; mt++)
#pragma unroll
            for (int r = 0; r < 4; r++) acc[mt][nt][r] *= inv;
    }

    if (waveM == 0) {            // Qn^T [n][m]
        short* Qb = Qnt + (size_t)b * N_ * CQ;
#pragma unroll
        for (int nt = 0; nt < 2; nt++) {
            int n = n0 + waveN * 32 + nt * 16 + ln;
#pragma unroll
            for (int mt = 0; mt < 4; mt++) {
                shortx4 v;
#pragma unroll
                for (int r = 0; r < 4; r++) v[r] = f2bf(acc[mt][nt][r]);
                *(shortx4*)(Qb + (size_t)n * CQ + mt * 16 + quad * 4) = v;
            }
        }
    } else {                     // Kn [m][n] + Ksum
        short* Kb = Kn + (size_t)b * CQ * N_;
#pragma unroll
        for (int mt = 0; mt < 4; mt++)
#pragma unroll
            for (int r = 0; r < 4; r++) {
                int m = mt * 16 + quad * 4 + r;
                float s = 0.f;
#pragma unroll
                for (int nt = 0; nt < 2; nt++) {
                    int n = n0 + waveN * 32 + nt * 16 + ln;
                    float v = acc[mt][nt][r];
                    Kb[(size_t)m * N_ + n] = f2bf(v);
                    s += v;
                }
                s += __shfl_xor(s, 1); s += __shfl_xor(s, 2);
                s += __shfl_xor(s, 4); s += __shfl_xor(s, 8);
                if (ln == 0) atomicAdd(&Ksum[b * CQ + m], s);
            }
    }
}

// ---------------------------------------------------------------------------
// K2: KXp[b][ks][m][j] = sum_{n in chunk} Kn[m][n]*x[j][n] (PLAIN stores,
// no atomics); xsum[j] += sum_n x[j][n] (tiny atomic).
// Round-0 structure otherwise. grid (jt=8, ks=8, b=8), block 256.
// ---------------------------------------------------------------------------
__global__ __launch_bounds__(256, 2) void k2_kx(
    const float* __restrict__ x, const short* __restrict__ Kn,
    float* __restrict__ KXp, float* __restrict__ xsum)
{
    const int jt = blockIdx.x, ks = blockIdx.y, b = blockIdx.z;
    const int j0 = jt * 64, nbase = ks * 512;
    const int tid = threadIdx.x;
    const int lane = tid & 63, wid = tid >> 6;
    const int quad = lane >> 4, ln = lane & 15;

    __shared__ short A_l[2][64][LS];    // Kn rows m
    __shared__ short B_l[2][64][LS];    // x rows j (bf16)

    const int rA = tid >> 2, oA = (tid & 3) * 8;
    const short* Kb = Kn + (size_t)b * CQ * N_;
    const float* xb = x + (size_t)b * C_ * N_;
    const short* As = Kb + (size_t)rA * N_ + nbase + oA;
    const float* Bs = xb + (size_t)(j0 + rA) * N_ + nbase + oA;

    float xsacc = 0.f;

    shortx8 aC = *(const shortx8*)As;
    float4 b0 = *(const float4*)(Bs);
    float4 b1 = *(const float4*)(Bs + 4);

    auto stage = [&](int buf, shortx8 a, float4 q0, float4 q1) {
        *(shortx8*)&A_l[buf][rA][oA] = a;
        const float* f0 = (const float*)&q0;
        const float* f1 = (const float*)&q1;
        shortx8 t;
#pragma unroll
        for (int i = 0; i < 4; i++) {
            t[i]     = f2bf(f0[i]); xsacc += f0[i];
            t[i + 4] = f2bf(f1[i]); xsacc += f1[i];
        }
        *(shortx8*)&B_l[buf][rA][oA] = t;
    };
    stage(0, aC, b0, b1);
    __syncthreads();

    const floatx4 z4 = {0.f, 0.f, 0.f, 0.f};
    floatx4 acc[4] = {z4, z4, z4, z4};

    int cur = 0;
    for (int it = 0; it < 16; ++it) {
        shortx8 aN; float4 n0v, n1v;
        if (it < 15) {
            const int off = (it + 1) * 32;
            aN  = *(const shortx8*)(As + off);
            n0v = *(const float4*)(Bs + off);
            n1v = *(const float4*)(Bs + off + 4);
        }
        shortx8 af[4];
#pragma unroll
        for (int mt = 0; mt < 4; mt++)
            af[mt] = ldf8(&A_l[cur][mt * 16 + ln][quad * 8]);
        shortx8 bf8 = ldf8(&B_l[cur][wid * 16 + ln][quad * 8]);
#pragma unroll
        for (int mt = 0; mt < 4; mt++)
            acc[mt] = __builtin_amdgcn_mfma_f32_16x16x32_bf16(af[mt], bf8, acc[mt], 0, 0, 0);
        if (it < 15) stage(cur ^ 1, aN, n0v, n1v);
        __syncthreads();
        cur ^= 1;
    }

    xsacc += __shfl_xor(xsacc, 1);
    xsacc += __shfl_xor(xsacc, 2);
    if ((tid & 3) == 0) atomicAdd(&xsum[b * C_ + j0 + rA], xsacc);

    float* KXb = KXp + ((size_t)b * 8 + ks) * CQ * C_;
#pragma unroll
    for (int mt = 0; mt < 4; mt++)
#pragma unroll
        for (int r = 0; r < 4; r++) {
            int m = mt * 16 + quad * 4 + r;
            KXb[(size_t)m * C_ + j0 + wid * 16 + ln] = acc[mt][r];
        }
}

// ---------------------------------------------------------------------------
// K3 (j-split x4): Mtp[b][js][c][m] = sum_{j in chunk128} Wv[c][j]*KX[m][j]
// (fp32 partials, plain stores); vsp2[b][js][c] = sum_chunk Wv[c][j]*xsum[j].
// KX[m][j] = sum_ks KXp summed during B-stage (L2-hot).
// grid (ct=8, js=4, b=8) = 256 blocks (4x the old 64), 4 iters each.
// ---------------------------------------------------------------------------
__global__ __launch_bounds__(256, 2) void k3_m(
    const float* __restrict__ KXp, const short* __restrict__ Wvb,
    const float* __restrict__ xsum,
    float* __restrict__ Mtp, float* __restrict__ vsp2)
{
    const int ct = blockIdx.x, js = blockIdx.y, b = blockIdx.z;
    const int c0 = ct * 64, jb = js * 128;
    const int tid = threadIdx.x;
    const int lane = tid & 63, wid = tid >> 6;
    const int quad = lane >> 4, ln = lane & 15;

    __shared__ short A_l[2][64][LS];   // Wv rows c (k = j 32-chunk)
    __shared__ short B_l[2][64][LS];   // KX rows m (bf16)
    __shared__ float xsl[128], vsp[4][64];

    if (tid < 128) xsl[tid] = xsum[(size_t)b * C_ + jb + tid];

    const int rA = tid >> 2, oA = (tid & 3) * 8;
    const short* As = Wvb + (size_t)(c0 + rA) * C_ + jb + oA;
    const float* Bs = KXp + ((size_t)b * 8 * CQ + rA) * C_ + jb + oA;
    const size_t PS = (size_t)CQ * C_;

    auto loadB = [&](int off, float4& o0, float4& o1) {
        float s0[4] = {0.f, 0.f, 0.f, 0.f}, s1[4] = {0.f, 0.f, 0.f, 0.f};
#pragma unroll
        for (int p = 0; p < 8; p++) {
            const float* q = Bs + p * PS + off;
            float4 u0 = *(const float4*)(q);
            float4 u1 = *(const float4*)(q + 4);
            const float* g0 = (const float*)&u0;
            const float* g1 = (const float*)&u1;
#pragma unroll
            for (int e = 0; e < 4; e++) { s0[e] += g0[e]; s1[e] += g1[e]; }
        }
        o0 = make_float4(s0[0], s0[1], s0[2], s0[3]);
        o1 = make_float4(s1[0], s1[1], s1[2], s1[3]);
    };

    shortx8 aC = *(const shortx8*)As;
    float4 b0, b1;
    loadB(0, b0, b1);

    auto stage = [&](int buf, shortx8 a, float4 q0, float4 q1) {
        *(shortx8*)&A_l[buf][rA][oA] = a;
        const float* f0 = (const float*)&q0;
        const float* f1 = (const float*)&q1;
        shortx8 t;
#pragma unroll
        for (int i = 0; i < 4; i++) { t[i] = f2bf(f0[i]); t[i + 4] = f2bf(f1[i]); }
        *(shortx8*)&B_l[buf][rA][oA] = t;
    };
    stage(0, aC, b0, b1);
    __syncthreads();

    const floatx4 z4 = {0.f, 0.f, 0.f, 0.f};
    floatx4 acc[4] = {z4, z4, z4, z4};
    float vsacc = 0.f;
    const int cv = tid & 63;

    int cur = 0;
    for (int it = 0; it < 4; ++it) {
        shortx8 aN; float4 n0v, n1v;
        if (it < 3) {
            const int off = (it + 1) * 32;
            aN = *(const shortx8*)(As + off);
            loadB(off, n0v, n1v);
        }
        shortx8 af[4];
#pragma unroll
        for (int ct2 = 0; ct2 < 4; ct2++)
            af[ct2] = ldf8(&A_l[cur][ct2 * 16 + ln][quad * 8]);
        shortx8 bf8 = ldf8(&B_l[cur][wid * 16 + ln][quad * 8]);
#pragma unroll
        for (int ct2 = 0; ct2 < 4; ct2++)
            acc[ct2] = __builtin_amdgcn_mfma_f32_16x16x32_bf16(af[ct2], bf8, acc[ct2], 0, 0, 0);
        // vs partial from staged Wv tile
#pragma unroll
        for (int jj = 0; jj < 8; jj++)
            vsacc += bf2f(A_l[cur][cv][wid * 8 + jj]) * xsl[it * 32 + wid * 8 + jj];
        if (it < 3) stage(cur ^ 1, aN, n0v, n1v);
        __syncthreads();
        cur ^= 1;
    }

    vsp[wid][cv] = vsacc;
    __syncthreads();
    if (tid < 64)
        vsp2[((size_t)b * 4 + js) * C_ + c0 + tid] =
            vsp[0][tid] + vsp[1][tid] + vsp[2][tid] + vsp[3][tid];

    const int m = wid * 16 + ln;
    float* Mb = Mtp + ((size_t)b * 4 + js) * C_ * CQ;
#pragma unroll
    for (int ct2 = 0; ct2 < 4; ct2++)
#pragma unroll
        for (int r = 0; r < 4; r++) {
            int c = ct2 * 16 + quad * 4 + r;
            Mb[(size_t)(c0 + c) * CQ + m] = acc[ct2][r];
        }
}

// ---------------------------------------------------------------------------
// K3B (combine): Mt[c][m] = f2bf(sum_js Mtp + Ksum[m]*bv[c]);
//                vs[c] = sum_js vsp2 + N*bv[c].
// grid (cb=32, b=8) = 256 blocks, 256 threads, ~16 KB reads/block.
// ---------------------------------------------------------------------------
__global__ __launch_bounds__(256) void k3b(
    const float* __restrict__ Mtp, const float* __restrict__ vsp2,
    const float* __restrict__ Ksum, const float* __restrict__ bv,
    short* __restrict__ Mt, float* __restrict__ vs)
{
    const int cb = blockIdx.x, b = blockIdx.y;
    const int c0 = cb * 16;
    const int tid = threadIdx.x;
    const int c = c0 + (tid >> 4), m0 = (tid & 15) * 4;
    const size_t PS = (size_t)C_ * CQ;

    const float* base = Mtp + (size_t)b * 4 * PS + (size_t)c * CQ + m0;
    float s[4] = {0.f, 0.f, 0.f, 0.f};
#pragma unroll
    for (int p = 0; p < 4; p++) {
        float4 u = *(const float4*)(base + p * PS);
        const float* g = (const float*)&u;
#pragma unroll
        for (int e = 0; e < 4; e++) s[e] += g[e];
    }
    const float bvc = bv[c];
    shortx4 o;
#pragma unroll
    for (int r = 0; r < 4; r++)
        o[r] = f2bf(s[r] + Ksum[b * CQ + m0 + r] * bvc);
    *(shortx4*)(Mt + ((size_t)b * C_ + c) * CQ + m0) = o;

    if (tid < 16) {
        const int cc = c0 + tid;
        float v = 0.f;
#pragma unroll
        for (int p = 0; p < 4; p++)
            v += vsp2[((size_t)b * 4 + p) * C_ + cc];
        vs[(size_t)b * C_ + cc] = v + (float)N_ * bv[cc];
    }
}

// ---------------------------------------------------------------------------
// K4: ts[n] = 1/(N + Qn[:,n].(Ksum+eps));
//     out[c][n] = gamma*ts[n]*(vs[c] + sum_m Qn[m][n]*Mt[c][m])
// ROUND-0 VERBATIM. grid (nt=32, ct=4, b=8), block 256.
// ---------------------------------------------------------------------------
__global__ __launch_bounds__(256, 2) void k4_out(
    const short* __restrict__ Qnt, const short* __restrict__ Mt,
    const float* __restrict__ vs, const float* __restrict__ Ksum,
    const float* __restrict__ gamma, float* __restrict__ out)
{
    const int nt = blockIdx.x, ct = blockIdx.y, b = blockIdx.z;
    const int n0 = nt * 128, c0 = ct * 128;
    const int tid = threadIdx.x;
    const int lane = tid & 63, wid = tid >> 6;
    const int waveC = wid >> 1, waveN = wid & 1;
    const int quad = lane >> 4, ln = lane & 15;

    __shared__ short A_l[128][LS2];   // Mt rows c (bf16), k=m
    __shared__ short B_l[128][LS2];   // Qnt rows n (bf16)
    __shared__ float tsl[128], vsl[128], Ks_l[64];

    {
        int c = tid >> 1, h = tid & 1;
        const short* src = Mt + ((size_t)b * C_ + c0 + c) * CQ + h * 32;
#pragma unroll
        for (int q = 0; q < 4; q++)
            *(shortx8*)&A_l[c][h * 32 + q * 8] = *(const shortx8*)(src + q * 8);
    }
    {
        int n = tid >> 1, h = tid & 1;
        const short* src = Qnt + ((size_t)b * N_ + n0 + n) * CQ + h * 32;
#pragma unroll
        for (int q = 0; q < 4; q++)
            *(shortx8*)&B_l[n][h * 32 + q * 8] = *(const shortx8*)(src + q * 8);
    }
    if (tid < 64)  Ks_l[tid] = Ksum[b * CQ + tid];
    if (tid < 128) vsl[tid]  = vs[(size_t)b * C_ + c0 + tid];
    __syncthreads();

    if (tid < 128) {
        const short* row = B_l[tid];
        float s = 0.f;
#pragma unroll
        for (int m = 0; m < 64; m++) s += bf2f(row[m]) * (Ks_l[m] + EPSF);
        tsl[tid] = 1.f / ((float)N_ + s);
    }
    __syncthreads();

    const floatx4 z4 = {0.f, 0.f, 0.f, 0.f};
    floatx4 acc[4][4];
#pragma unroll
    for (int i = 0; i < 4; i++)
#pragma unroll
        for (int j = 0; j < 4; j++) acc[i][j] = z4;

#pragma unroll
    for (int kc = 0; kc < 2; kc++) {
        shortx8 af[4];
#pragma unroll
        for (int ct2 = 0; ct2 < 4; ct2++)
            af[ct2] = ldf8(&A_l[waveC * 64 + ct2 * 16 + ln][kc * 32 + quad * 8]);
#pragma unroll
        for (int nt2 = 0; nt2 < 4; nt2++) {
            shortx8 bf8 = ldf8(&B_l[waveN * 64 + nt2 * 16 + ln][kc * 32 + quad * 8]);
#pragma unroll
            for (int ct2 = 0; ct2 < 4; ct2++)
                acc[ct2][nt2] = __builtin_amdgcn_mfma_f32_16x16x32_bf16(af[ct2], bf8, acc[ct2][nt2], 0, 0, 0);
        }
    }

    const float g = gamma[0];
    float* ob = out + (size_t)b * C_ * N_;
#pragma unroll
    for (int ct2 = 0; ct2 < 4; ct2++)
#pragma unroll
        for (int r = 0; r < 4; r++) {
            int cl = waveC * 64 + ct2 * 16 + quad * 4 + r;
            float vc = vsl[cl];
#pragma unroll
            for (int nt2 = 0; nt2 < 4; nt2++) {
                int nl = waveN * 64 + nt2 * 16 + ln;
                ob[(size_t)(c0 + cl) * N_ + n0 + nl] = g * tsl[nl] * (vc + acc[ct2][nt2][r]);
            }
        }
}

// ---------------------------------------------------------------------------
extern "C" void kernel_launch(void* const* d_in, const int* in_sizes, int n_in,
                              void* d_out, int out_size, void* d_ws, size_t ws_size,
                              hipStream_t stream)
{
    (void)in_sizes; (void)n_in; (void)out_size; (void)ws_size;
    const float* x     = (const float*)d_in[0];
    const float* Wq    = (const float*)d_in[1];
    const float* bq    = (const float*)d_in[2];
    const float* Wk    = (const float*)d_in[3];
    const float* bk    = (const float*)d_in[4];
    const float* Wv    = (const float*)d_in[5];
    const float* bv    = (const float*)d_in[6];
    const float* gamma = (const float*)d_in[7];
    float* out = (float*)d_out;

    short* Qnt  = (short*)d_ws;                         // [8][4096][64] bf16
    short* Kn   = Qnt + (size_t)B_ * N_ * CQ;           // [8][64][4096] bf16
    float* Ksum = (float*)(Kn + (size_t)B_ * CQ * N_);  // [8][64]
    float* xsum = Ksum + B_ * CQ;                       // [8][512]
    float* KXp  = xsum + B_ * C_;                       // [8][8][64][512] fp32
    float* Mtp  = KXp + (size_t)B_ * 8 * CQ * C_;       // [8][4][512][64] fp32
    float* vsp2 = Mtp + (size_t)B_ * 4 * C_ * CQ;       // [8][4][512]
    short* Mt   = (short*)(vsp2 + (size_t)B_ * 4 * C_); // [8][512][64] bf16
    float* vs   = (float*)(Mt + (size_t)B_ * C_ * CQ);  // [8][512]
    short* Wqk  = (short*)(vs + B_ * C_);               // [128][512] bf16
    short* Wvb  = Wqk + 2 * CQ * C_;                    // [512][512] bf16

    size_t zbytes = (size_t)(B_ * CQ + B_ * C_) * 4;    // Ksum + xsum only
    hipMemsetAsync(Ksum, 0, zbytes, stream);

    pcast <<<dim3(320),      256, 0, stream>>>(Wq, Wk, Wv, Wqk, Wvb);
    k1_qk <<<dim3(64, 8),    256, 0, stream>>>(x, Wqk, bq, bk, Qnt, Kn, Ksum);
    k2_kx <<<dim3(8, 8, 8),  256, 0, stream>>>(x, Kn, KXp, xsum);
    k3_m  <<<dim3(8, 4, 8),  256, 0, stream>>>(KXp, Wvb, xsum, Mtp, vsp2);
    k3b   <<<dim3(32, 8),    256, 0, stream>>>(Mtp, vsp2, Ksum, bv, Mt, vs);
    k4_out<<<dim3(32, 4, 8), 256, 0, stream>>>(Qnt, Mt, vs, Ksum, gamma, out);
}